// Round 2
// baseline (624.868 us; speedup 1.0000x reference)
//
#include <hip/hip_runtime.h>
#include <stdint.h>

#define NNODES 32768
#define NREL 10
#define NBASES 4
#define DIM 256
#define NEDGE 524288
#define NCOL 1280   /* NBASES*DIM + DIM (root) */

typedef __attribute__((ext_vector_type(8))) short bf16x8;
typedef __attribute__((ext_vector_type(4))) float f32x4;

__device__ __forceinline__ float bf2f(unsigned short u){
  union { unsigned int i; float f; } v; v.i = ((unsigned int)u) << 16; return v.f;
}
__device__ __forceinline__ unsigned short f2bf(float f){
  union { float f; unsigned int i; } v; v.f = f;
  unsigned int x = v.i;
  unsigned int r = (x + 0x7FFFu + ((x >> 16) & 1u)) >> 16;
  return (unsigned short)r;
}

// ----------------------------------------------------- fp32 -> bf16 convert
__global__ __launch_bounds__(256) void conv_kernel(const float* __restrict__ in,
                                                   unsigned short* __restrict__ out)
{
  int i = blockIdx.x * 256 + threadIdx.x;      // one float4 per thread
  float4 v = ((const float4*)in)[i];
  ushort4 o; o.x = f2bf(v.x); o.y = f2bf(v.y); o.z = f2bf(v.z); o.w = f2bf(v.w);
  ((ushort4*)out)[i] = o;
}

// ---------------------------------------------------------------- histogram
__global__ void hist_kernel(const int* __restrict__ ec, const int* __restrict__ rel,
                            int* __restrict__ cnt_rd, int* __restrict__ deg)
{
  int e = blockIdx.x * 256 + threadIdx.x;   // grid covers E exactly
  int d = ec[NEDGE + e];
  int r = rel[e];
  atomicAdd(&cnt_rd[r * NNODES + d], 1);
  atomicAdd(&deg[d], 1);
}

// ------------------------------------------------- exclusive scan over deg[]
__global__ void scan_kernel(const int* __restrict__ deg, int* __restrict__ offs)
{
  __shared__ int sh[1024];
  __shared__ int carry;
  int tid = threadIdx.x;
  if (tid == 0) carry = 0;
  __syncthreads();
  for (int base = 0; base < NNODES; base += 1024){
    int v = deg[base + tid];
    sh[tid] = v;
    __syncthreads();
    for (int off = 1; off < 1024; off <<= 1){
      int t = (tid >= off) ? sh[tid - off] : 0;
      __syncthreads();
      sh[tid] += t;
      __syncthreads();
    }
    int c = carry;
    offs[base + tid] = c + sh[tid] - v;   // exclusive
    __syncthreads();
    if (tid == 0) carry = c + sh[1023];
    __syncthreads();
  }
  if (tid == 0) offs[NNODES] = carry;
}

// ------------------------------------------------------- bucket scatter sort
__global__ void scatter_kernel(const int* __restrict__ ec, const int* __restrict__ rel,
                               const int* __restrict__ offs, int* __restrict__ cursor,
                               const int* __restrict__ cnt_rd,
                               unsigned int* __restrict__ srcrel, float* __restrict__ einv)
{
  int e = blockIdx.x * 256 + threadIdx.x;
  int s = ec[e];
  int d = ec[NEDGE + e];
  int r = rel[e];
  int p = offs[d] + atomicAdd(&cursor[d], 1);
  srcrel[p] = ((unsigned int)s << 4) | (unsigned int)r;
  einv[p] = 1.0f / (float)cnt_rd[r * NNODES + d];
}

// --------------------- Wt[col][k] = concat(basis, root)^T, fp32 -> bf16
__global__ __launch_bounds__(256) void build_wt(
    const float* __restrict__ basis,  // [NBASES, DIM, DIM] (b,i,o) fp32
    const float* __restrict__ root,   // [DIM, DIM] (i,o) fp32
    unsigned short* __restrict__ Wt)  // [NCOL, DIM] (col, k=i) bf16
{
  int col = blockIdx.x;     // 0..NCOL-1
  int i   = threadIdx.x;    // k index 0..255
  float v;
  if (col < NBASES * DIM){
    int b = col >> 8, c = col & 255;
    v = basis[((size_t)b * DIM + i) * DIM + c];
  } else {
    int c = col - NBASES * DIM;
    v = root[(size_t)i * DIM + c];
  }
  Wt[(size_t)col * DIM + i] = f2bf(v);
}

// ------------------------------------------------ MFMA GEMM: Y = X @ Wt^T
// X [M,256] bf16 row-major, Wt [NCOL,256] bf16 row-major (i.e. B^T), Y [M,NCOL]
__global__ __launch_bounds__(256) void gemm_bt(
    const unsigned short* __restrict__ X,
    const unsigned short* __restrict__ Wt,
    unsigned short* __restrict__ Y)
{
  __shared__ short As[128 * 32];
  __shared__ short Bs[128 * 32];
  int tid  = threadIdx.x;
  int m0   = blockIdx.x * 128;
  int n0   = blockIdx.y * 128;
  int lane = tid & 63;
  int wave = tid >> 6;
  int wm = wave & 1, wn = wave >> 1;
  int lq = lane >> 4, lr = lane & 15;

  f32x4 zero = {0.0f, 0.0f, 0.0f, 0.0f};
  f32x4 acc[4][4];
#pragma unroll
  for (int i = 0; i < 4; i++)
#pragma unroll
    for (int j = 0; j < 4; j++) acc[i][j] = zero;

  for (int k0 = 0; k0 < DIM; k0 += 32){
    __syncthreads();
#pragma unroll
    for (int i = 0; i < 2; i++){
      int c = tid + i * 256;          // 0..511 chunks of 8 bf16
      int row = c >> 2, kc = c & 3;
      bf16x8 va = *(const bf16x8*)(X  + (size_t)(m0 + row) * DIM + (k0 + kc * 8));
      bf16x8 vb = *(const bf16x8*)(Wt + (size_t)(n0 + row) * DIM + (k0 + kc * 8));
      *(bf16x8*)(As + row * 32 + kc * 8) = va;
      *(bf16x8*)(Bs + row * 32 + kc * 8) = vb;
    }
    __syncthreads();

    bf16x8 af[4], bfr[4];
#pragma unroll
    for (int i = 0; i < 4; i++)
      af[i] = *(const bf16x8*)(As + (wm * 64 + i * 16 + lr) * 32 + lq * 8);
#pragma unroll
    for (int j = 0; j < 4; j++)
      bfr[j] = *(const bf16x8*)(Bs + (wn * 64 + j * 16 + lr) * 32 + lq * 8);
#pragma unroll
    for (int i = 0; i < 4; i++)
#pragma unroll
      for (int j = 0; j < 4; j++)
        acc[i][j] = __builtin_amdgcn_mfma_f32_16x16x32_bf16(af[i], bfr[j], acc[i][j], 0, 0, 0);
  }

  // epilogue: C/D mapping col=lane&15, row=(lane>>4)*4+reg  [verified m89/m91]
#pragma unroll
  for (int i = 0; i < 4; i++)
#pragma unroll
    for (int j = 0; j < 4; j++)
#pragma unroll
      for (int r = 0; r < 4; r++){
        int gm = m0 + wm * 64 + i * 16 + lq * 4 + r;
        int gn = n0 + wn * 64 + j * 16 + lr;
        Y[(size_t)gm * NCOL + gn] = f2bf(acc[i][j][r]);
      }
}

// ----------------------------------------- aggregation: one wave per dst node
// out_h != null : write bf16 (+optional relu)   out_f != null : write fp32
__global__ __launch_bounds__(64) void agg_kernel(
    const unsigned short* __restrict__ xb,     // [NNODES, NCOL] bf16
    const int* __restrict__ offs,
    const unsigned int* __restrict__ srcrel,
    const float* __restrict__ einv,
    const float* __restrict__ comp,            // [NREL*NBASES] fp32
    const float* __restrict__ bias,            // [DIM] fp32
    unsigned short* __restrict__ out_h,        // [NNODES, DIM] bf16 or null
    float* __restrict__ out_f,                 // [NNODES, DIM] fp32 or null
    int do_relu)
{
  __shared__ float scomp[NREL * NBASES];
  int lane = threadIdx.x;
  if (lane < NREL * NBASES) scomp[lane] = comp[lane];
  __syncthreads();

  int d = blockIdx.x;
  int col = lane * 4;

  // init = x@root + bias  (root product sits in xb columns [1024,1280))
  ushort4 xr = *(const ushort4*)(xb + (size_t)d * NCOL + NBASES * DIM + col);
  float4  bs = *(const float4*)(bias + col);
  float a0 = bf2f(xr.x) + bs.x;
  float a1 = bf2f(xr.y) + bs.y;
  float a2 = bf2f(xr.z) + bs.z;
  float a3 = bf2f(xr.w) + bs.w;

  int e0 = offs[d], e1 = offs[d + 1];
  for (int e = e0; e < e1; ++e){
    unsigned int sr = srcrel[e];
    float inv = einv[e];
    int s = (int)(sr >> 4);
    int r = (int)(sr & 15u);
    const unsigned short* base = xb + (size_t)s * NCOL + col;
    float m0 = 0.f, m1 = 0.f, m2 = 0.f, m3 = 0.f;
#pragma unroll
    for (int b = 0; b < NBASES; b++){
      ushort4 v = *(const ushort4*)(base + b * DIM);
      float cf = scomp[r * NBASES + b];
      m0 += cf * bf2f(v.x); m1 += cf * bf2f(v.y);
      m2 += cf * bf2f(v.z); m3 += cf * bf2f(v.w);
    }
    a0 += inv * m0; a1 += inv * m1; a2 += inv * m2; a3 += inv * m3;
  }

  if (do_relu){
    a0 = fmaxf(a0, 0.f); a1 = fmaxf(a1, 0.f);
    a2 = fmaxf(a2, 0.f); a3 = fmaxf(a3, 0.f);
  }
  if (out_h){
    ushort4 o; o.x = f2bf(a0); o.y = f2bf(a1); o.z = f2bf(a2); o.w = f2bf(a3);
    *(ushort4*)(out_h + (size_t)d * DIM + col) = o;
  } else {
    float4 o; o.x = a0; o.y = a1; o.z = a2; o.w = a3;
    *(float4*)(out_f + (size_t)d * DIM + col) = o;
  }
}

// ---------------------------------------------------------------------------
extern "C" void kernel_launch(void* const* d_in, const int* in_sizes, int n_in,
                              void* d_out, int out_size, void* d_ws, size_t ws_size,
                              hipStream_t stream)
{
  const float* x      = (const float*)d_in[0];
  const int*   ec     = (const int*)d_in[3];   // [2,E] src|dst
  const int*   rel    = (const int*)d_in[4];   // [E]
  const float* basis0 = (const float*)d_in[5];
  const float* comp0  = (const float*)d_in[6];
  const float* root0  = (const float*)d_in[7];
  const float* bias0  = (const float*)d_in[8];
  const float* basis1 = (const float*)d_in[9];
  const float* comp1  = (const float*)d_in[10];
  const float* root1  = (const float*)d_in[11];
  const float* bias1  = (const float*)d_in[12];

  char* p = (char*)d_ws;
  unsigned short* xb = (unsigned short*)p; p += (size_t)NNODES * NCOL * 2;   // 83.9 MB
  unsigned short* Xh = (unsigned short*)p; p += (size_t)NNODES * DIM * 2;    // 16.8 MB
  unsigned short* h  = (unsigned short*)p; p += (size_t)NNODES * DIM * 2;    // 16.8 MB
  unsigned short* Wt = (unsigned short*)p; p += (size_t)NCOL * DIM * 2;      // 0.66 MB
  int* cnt_rd = (int*)p;       p += (size_t)NREL * NNODES * 4;               // 1.3 MB
  int* deg    = (int*)p;       p += (size_t)NNODES * 4;
  int* cursor = (int*)p;       p += (size_t)NNODES * 4;
  int* offs   = (int*)p;       p += (size_t)(NNODES + 1) * 4;
  unsigned int* srcrel = (unsigned int*)p; p += (size_t)NEDGE * 4;           // 2 MB
  float* einv = (float*)p;     p += (size_t)NEDGE * 4;                       // 2 MB

  // zero cnt_rd + deg + cursor (contiguous)
  hipMemsetAsync(cnt_rd, 0, ((size_t)NREL * NNODES + 2 * (size_t)NNODES) * 4, stream);

  // graph structure: shared by both layers
  hist_kernel   <<<NEDGE / 256, 256, 0, stream>>>(ec, rel, cnt_rd, deg);
  scan_kernel   <<<1, 1024, 0, stream>>>(deg, offs);
  scatter_kernel<<<NEDGE / 256, 256, 0, stream>>>(ec, rel, offs, cursor, cnt_rd, srcrel, einv);

  // x fp32 -> bf16
  conv_kernel<<<(NNODES * DIM / 4) / 256, 256, 0, stream>>>(x, Xh);

  // ---- layer 0 ----
  build_wt<<<NCOL, 256, 0, stream>>>(basis0, root0, Wt);
  gemm_bt <<<dim3(NNODES / 128, NCOL / 128), 256, 0, stream>>>(Xh, Wt, xb);
  agg_kernel<<<NNODES, 64, 0, stream>>>(xb, offs, srcrel, einv, comp0, bias0, h, nullptr, 1);

  // ---- layer 1 ----
  build_wt<<<NCOL, 256, 0, stream>>>(basis1, root1, Wt);
  gemm_bt <<<dim3(NNODES / 128, NCOL / 128), 256, 0, stream>>>(h, Wt, xb);
  agg_kernel<<<NNODES, 64, 0, stream>>>(xb, offs, srcrel, einv, comp1, bias1,
                                        nullptr, (float*)d_out, 0);
}

// Round 3
// 590.920 us; speedup vs baseline: 1.0574x; 1.0574x over previous
//
#include <hip/hip_runtime.h>
#include <stdint.h>

#define NNODES 32768
#define NREL 10
#define NBASES 4
#define DIM 256
#define NEDGE 524288
#define NSEG (NREL * NNODES)        /* 327680 */
#define GSEG (5 * NNODES)           /* segments per relation-group */
#define KBASE 1280                  /* 5 rels * 256 */

typedef __attribute__((ext_vector_type(8))) short bf16x8;
typedef __attribute__((ext_vector_type(4))) float f32x4;

__device__ __forceinline__ float bf2f(unsigned short u){
  union { unsigned int i; float f; } v; v.i = ((unsigned int)u) << 16; return v.f;
}
__device__ __forceinline__ unsigned short f2bf(float f){
  union { float f; unsigned int i; } v; v.f = f;
  unsigned int x = v.i;
  unsigned int r = (x + 0x7FFFu + ((x >> 16) & 1u)) >> 16;
  return (unsigned short)r;
}
// async global->LDS, 16 bytes per lane; LDS dest must be linear in lane*16
__device__ __forceinline__ void gll16(const void* g, void* l){
  __builtin_amdgcn_global_load_lds((const __attribute__((address_space(1))) void*)g,
                                   (__attribute__((address_space(3))) void*)l, 16, 0, 0);
}

// ----------------------------------------------------- fp32 -> bf16 convert
__global__ __launch_bounds__(256) void conv_kernel(const float* __restrict__ in,
                                                   unsigned short* __restrict__ out)
{
  int i = blockIdx.x * 256 + threadIdx.x;
  float4 v = ((const float4*)in)[i];
  ushort4 o; o.x = f2bf(v.x); o.y = f2bf(v.y); o.z = f2bf(v.z); o.w = f2bf(v.w);
  ((ushort4*)out)[i] = o;
}

// ------------------------------------------------- histogram over segments
__global__ void hist2(const int* __restrict__ ec, const int* __restrict__ rel,
                      int* __restrict__ cnt_seg)
{
  int e = blockIdx.x * 256 + threadIdx.x;
  int d = ec[NEDGE + e];
  int r = rel[e];
  atomicAdd(&cnt_seg[(r << 15) + d], 1);
}

// --------------------------------------- 3-kernel exclusive scan over NSEG
__global__ __launch_bounds__(1024) void scan1(const int* __restrict__ cnt,
                                              int* __restrict__ offs, int* __restrict__ blksum)
{
  __shared__ int sh[1024];
  int tid = threadIdx.x; int gid = blockIdx.x * 1024 + tid;
  int v = cnt[gid]; sh[tid] = v; __syncthreads();
  for (int off = 1; off < 1024; off <<= 1){
    int t = (tid >= off) ? sh[tid - off] : 0;
    __syncthreads(); sh[tid] += t; __syncthreads();
  }
  offs[gid] = sh[tid] - v;
  if (tid == 1023) blksum[blockIdx.x] = sh[1023];
}
__global__ __launch_bounds__(512) void scan2(int* __restrict__ blksum, int* __restrict__ offs_last)
{
  __shared__ int sh[512];
  int tid = threadIdx.x;
  int v = (tid < NSEG / 1024) ? blksum[tid] : 0;
  sh[tid] = v; __syncthreads();
  for (int off = 1; off < 512; off <<= 1){
    int t = (tid >= off) ? sh[tid - off] : 0;
    __syncthreads(); sh[tid] += t; __syncthreads();
  }
  if (tid < NSEG / 1024) blksum[tid] = sh[tid] - v;
  if (tid == 511) offs_last[0] = sh[511];
}
__global__ __launch_bounds__(1024) void scan3(int* __restrict__ offs, const int* __restrict__ blksum)
{
  int gid = blockIdx.x * 1024 + threadIdx.x;
  offs[gid] += blksum[blockIdx.x];
}

// ------------------------------------------------------- bucket scatter sort
__global__ void scatter2(const int* __restrict__ ec, const int* __restrict__ rel,
                         const int* __restrict__ offs, int* __restrict__ cursor,
                         int* __restrict__ ssrc)
{
  int e = blockIdx.x * 256 + threadIdx.x;
  int s = ec[e];
  int d = ec[NEDGE + e];
  int r = rel[e];
  int seg = (r << 15) + d;
  int p = offs[seg] + atomicAdd(&cursor[seg], 1);
  ssrc[p] = s;
}

// ----------------- Wt[n][k] = premixed weights, bf16  (k<1280: W_r, else root)
__global__ __launch_bounds__(256) void build_wt2(
    const float* __restrict__ basis,   // [NB,256,256] fp32
    const float* __restrict__ comp5,   // &comp[group*5*NB]
    const float* __restrict__ root,    // [256,256] fp32 or null
    unsigned short* __restrict__ Wt, int Kw)
{
  int k = blockIdx.x, n = threadIdx.x;
  float v;
  if (k < KBASE){
    int rl = k >> 8, i = k & 255;
    const float* c = comp5 + rl * NBASES;
    v = 0.f;
#pragma unroll
    for (int b = 0; b < NBASES; b++)
      v += c[b] * basis[((size_t)b * 256 + i) * 256 + n];
  } else {
    v = root[(size_t)(k - KBASE) * 256 + n];
  }
  Wt[(size_t)n * Kw + k] = f2bf(v);
}

// ---------------------- segment means in x-space: one wave per (dst,rel) seg
__global__ __launch_bounds__(256) void agg2(
    const unsigned short* __restrict__ Xin,   // [N,256] bf16
    const int* __restrict__ offs,             // [NSEG+1]
    const int* __restrict__ ssrc,             // sorted src ids
    unsigned short* __restrict__ xmean,       // [N, KBASE] bf16
    int group)
{
  int w = blockIdx.x * 4 + (threadIdx.x >> 6);      // 0..GSEG-1
  int seg = group * GSEG + w;
  int d  = seg & (NNODES - 1);
  int r5 = (seg >> 15) - group * 5;
  int col = (threadIdx.x & 63) * 4;
  int e0 = offs[seg], e1 = offs[seg + 1];
  float a0 = 0.f, a1 = 0.f, a2 = 0.f, a3 = 0.f;
  for (int e = e0; e < e1; ++e){
    int s = ssrc[e];
    ushort4 v = *(const ushort4*)(Xin + (size_t)s * 256 + col);
    a0 += bf2f(v.x); a1 += bf2f(v.y); a2 += bf2f(v.z); a3 += bf2f(v.w);
  }
  float inv = (e1 > e0) ? 1.0f / (float)(e1 - e0) : 0.0f;
  ushort4 o;
  o.x = f2bf(a0 * inv); o.y = f2bf(a1 * inv);
  o.z = f2bf(a2 * inv); o.w = f2bf(a3 * inv);
  *(ushort4*)(xmean + (size_t)d * KBASE + r5 * 256 + col) = o;
}

// ------------- MFMA GEMM: Y[M,256] (+)= [xmean | ext] @ Wt^T   (Wt [256,Kw])
// mode 0: Yacc = acc + bias ; mode 1: h = relu(acc+Yacc) bf16 ; mode 2: out = acc+Yacc fp32
__global__ __launch_bounds__(256) void gemm2(
    const unsigned short* __restrict__ A0,   // xmean [M,KBASE]
    const unsigned short* __restrict__ A1,   // ext [M,256] or null
    const unsigned short* __restrict__ Wt,   // [256,Kw]
    int Kw,
    const float* __restrict__ bias,
    float* __restrict__ Yacc,
    unsigned short* __restrict__ outh,
    float* __restrict__ outf,
    int mode)
{
  __shared__ __attribute__((aligned(16))) short As[128 * 32];
  __shared__ __attribute__((aligned(16))) short Bs[128 * 32];
  int tid  = threadIdx.x;
  int m0   = blockIdx.x * 128;
  int n0   = blockIdx.y * 128;
  int lane = tid & 63;
  int wave = tid >> 6;
  int wm = wave & 1, wn = wave >> 1;
  int lq = lane >> 4, lr = lane & 15;

  f32x4 zero = {0.f, 0.f, 0.f, 0.f};
  f32x4 acc[4][4];
#pragma unroll
  for (int i = 0; i < 4; i++)
#pragma unroll
    for (int j = 0; j < 4; j++) acc[i][j] = zero;

  for (int k0 = 0; k0 < Kw; k0 += 32){
    __syncthreads();
#pragma unroll
    for (int i = 0; i < 2; i++){
      int g = tid + i * 256;            // 16B granule id, 0..511
      int row = g >> 2, c16 = g & 3;
      const unsigned short* ga;
      if (k0 < KBASE)
        ga = A0 + (size_t)(m0 + row) * KBASE + k0 + c16 * 8;
      else
        ga = A1 + (size_t)(m0 + row) * 256 + (k0 - KBASE) + c16 * 8;
      gll16(ga, As + g * 8);
      const unsigned short* gb = Wt + (size_t)(n0 + row) * Kw + k0 + c16 * 8;
      gll16(gb, Bs + g * 8);
    }
    __syncthreads();

    bf16x8 af[4], bfr[4];
#pragma unroll
    for (int i = 0; i < 4; i++)
      af[i] = *(const bf16x8*)(As + (wm * 64 + i * 16 + lr) * 32 + lq * 8);
#pragma unroll
    for (int j = 0; j < 4; j++)
      bfr[j] = *(const bf16x8*)(Bs + (wn * 64 + j * 16 + lr) * 32 + lq * 8);
#pragma unroll
    for (int i = 0; i < 4; i++)
#pragma unroll
      for (int j = 0; j < 4; j++)
        acc[i][j] = __builtin_amdgcn_mfma_f32_16x16x32_bf16(af[i], bfr[j], acc[i][j], 0, 0, 0);
  }

  // C/D mapping: col=lane&15, row=(lane>>4)*4+reg  [m89/m91]
#pragma unroll
  for (int i = 0; i < 4; i++)
#pragma unroll
    for (int j = 0; j < 4; j++)
#pragma unroll
      for (int r = 0; r < 4; r++){
        int gm = m0 + wm * 64 + i * 16 + lq * 4 + r;
        int gn = n0 + wn * 64 + j * 16 + lr;
        size_t idx = (size_t)gm * 256 + gn;
        float v = acc[i][j][r];
        if (mode == 0){
          Yacc[idx] = v + bias[gn];
        } else {
          v += Yacc[idx];
          if (mode == 1) outh[idx] = f2bf(fmaxf(v, 0.f));
          else           outf[idx] = v;
        }
      }
}

// ---------------------------------------------------------------------------
extern "C" void kernel_launch(void* const* d_in, const int* in_sizes, int n_in,
                              void* d_out, int out_size, void* d_ws, size_t ws_size,
                              hipStream_t stream)
{
  const float* x      = (const float*)d_in[0];
  const int*   ec     = (const int*)d_in[3];
  const int*   rel    = (const int*)d_in[4];
  const float* basis0 = (const float*)d_in[5];
  const float* comp0  = (const float*)d_in[6];
  const float* root0  = (const float*)d_in[7];
  const float* bias0  = (const float*)d_in[8];
  const float* basis1 = (const float*)d_in[9];
  const float* comp1  = (const float*)d_in[10];
  const float* root1  = (const float*)d_in[11];
  const float* bias1  = (const float*)d_in[12];

  char* p = (char*)d_ws;
  unsigned short* xmean = (unsigned short*)p; p += (size_t)NNODES * KBASE * 2;  // 83.9 MB
  unsigned short* Xh    = (unsigned short*)p; p += (size_t)NNODES * DIM * 2;    // 16.8
  unsigned short* h     = (unsigned short*)p; p += (size_t)NNODES * DIM * 2;    // 16.8
  float*          Yacc  = (float*)p;          p += (size_t)NNODES * DIM * 4;    // 33.6
  unsigned short* Wt    = (unsigned short*)p; p += (size_t)256 * 1536 * 2;      // 0.79
  int* cnt_seg = (int*)p;  p += (size_t)NSEG * 4;                               // 1.31
  int* cursor  = (int*)p;  p += (size_t)NSEG * 4;                               // 1.31
  int* offs    = (int*)p;  p += (size_t)(NSEG + 1) * 4 + 12;                    // pad->16B
  int* blksum  = (int*)p;  p += 4096;
  int* ssrc    = (int*)p;  p += (size_t)NEDGE * 4;                              // 2.1

  // zero cnt_seg + cursor (contiguous)
  hipMemsetAsync(cnt_seg, 0, (size_t)2 * NSEG * 4, stream);

  // ---- graph preprocessing (shared by both layers) ----
  hist2   <<<NEDGE / 256, 256, 0, stream>>>(ec, rel, cnt_seg);
  scan1   <<<NSEG / 1024, 1024, 0, stream>>>(cnt_seg, offs, blksum);
  scan2   <<<1, 512, 0, stream>>>(blksum, offs + NSEG);
  scan3   <<<NSEG / 1024, 1024, 0, stream>>>(offs, blksum);
  scatter2<<<NEDGE / 256, 256, 0, stream>>>(ec, rel, offs, cursor, ssrc);

  conv_kernel<<<(NNODES * DIM / 4) / 256, 256, 0, stream>>>(x, Xh);

  dim3 ggrid(NNODES / 128, 2);

  // ---- layer 0 ----
  build_wt2<<<1536, 256, 0, stream>>>(basis0, comp0, root0, Wt, 1536);
  agg2<<<GSEG / 4, 256, 0, stream>>>(Xh, offs, ssrc, xmean, 0);
  gemm2<<<ggrid, 256, 0, stream>>>(xmean, Xh, Wt, 1536, bias0, Yacc, nullptr, nullptr, 0);
  build_wt2<<<1280, 256, 0, stream>>>(basis0, comp0 + 5 * NBASES, nullptr, Wt, 1280);
  agg2<<<GSEG / 4, 256, 0, stream>>>(Xh, offs, ssrc, xmean, 1);
  gemm2<<<ggrid, 256, 0, stream>>>(xmean, nullptr, Wt, 1280, nullptr, Yacc, h, nullptr, 1);

  // ---- layer 1 ----
  build_wt2<<<1536, 256, 0, stream>>>(basis1, comp1, root1, Wt, 1536);
  agg2<<<GSEG / 4, 256, 0, stream>>>(h, offs, ssrc, xmean, 0);
  gemm2<<<ggrid, 256, 0, stream>>>(xmean, h, Wt, 1536, bias1, Yacc, nullptr, nullptr, 0);
  build_wt2<<<1280, 256, 0, stream>>>(basis1, comp1 + 5 * NBASES, nullptr, Wt, 1280);
  agg2<<<GSEG / 4, 256, 0, stream>>>(h, offs, ssrc, xmean, 1);
  gemm2<<<ggrid, 256, 0, stream>>>(xmean, nullptr, Wt, 1280, nullptr, Yacc, nullptr,
                                   (float*)d_out, 2);
}

// Round 4
// 435.834 us; speedup vs baseline: 1.4337x; 1.3558x over previous
//
#include <hip/hip_runtime.h>
#include <stdint.h>

#define NNODES 32768
#define NREL 10
#define NBASES 4
#define DIM 256
#define NEDGE 524288
#define KW 1280                 /* 4*256 basis + 256 root */
#define KBASE 1024              /* z width */

typedef __attribute__((ext_vector_type(8))) short bf16x8;
typedef __attribute__((ext_vector_type(4))) float f32x4;

__device__ __forceinline__ float bf2f(unsigned short u){
  union { unsigned int i; float f; } v; v.i = ((unsigned int)u) << 16; return v.f;
}
__device__ __forceinline__ unsigned short f2bf(float f){
  union { float f; unsigned int i; } v; v.f = f;
  unsigned int x = v.i;
  unsigned int r = (x + 0x7FFFu + ((x >> 16) & 1u)) >> 16;
  return (unsigned short)r;
}
__device__ __forceinline__ void gll16(const void* g, void* l){
  __builtin_amdgcn_global_load_lds((const __attribute__((address_space(1))) void*)g,
                                   (__attribute__((address_space(3))) void*)l, 16, 0, 0);
}

// ----------------------------------------------------- fp32 -> bf16 convert
__global__ __launch_bounds__(256) void conv_kernel(const float* __restrict__ in,
                                                   unsigned short* __restrict__ out)
{
  int i = blockIdx.x * 256 + threadIdx.x;
  float4 v = ((const float4*)in)[i];
  ushort4 o; o.x = f2bf(v.x); o.y = f2bf(v.y); o.z = f2bf(v.z); o.w = f2bf(v.w);
  ((ushort4*)out)[i] = o;
}

// ------------------------------------------- histogram: per-(r,d) and per-d
__global__ void hist_kernel(const int* __restrict__ ec, const int* __restrict__ rel,
                            int* __restrict__ cnt_rd, int* __restrict__ deg)
{
  int e = blockIdx.x * 256 + threadIdx.x;
  int d = ec[NEDGE + e];
  int r = rel[e];
  atomicAdd(&cnt_rd[(r << 15) + d], 1);
  atomicAdd(&deg[d], 1);
}

// ------------------------------------- exclusive scan over deg[] (one block)
__global__ void scan_kernel(const int* __restrict__ deg, int* __restrict__ offs)
{
  __shared__ int sh[1024];
  __shared__ int carry;
  int tid = threadIdx.x;
  if (tid == 0) carry = 0;
  __syncthreads();
  for (int base = 0; base < NNODES; base += 1024){
    int v = deg[base + tid];
    sh[tid] = v;
    __syncthreads();
    for (int off = 1; off < 1024; off <<= 1){
      int t = (tid >= off) ? sh[tid - off] : 0;
      __syncthreads();
      sh[tid] += t;
      __syncthreads();
    }
    int c = carry;
    offs[base + tid] = c + sh[tid] - v;
    __syncthreads();
    if (tid == 0) carry = c + sh[1023];
    __syncthreads();
  }
  if (tid == 0) offs[NNODES] = carry;
}

// --------------------------- bucket scatter: sort by dst, pack (src,rel,inv)
__global__ void scatter_kernel(const int* __restrict__ ec, const int* __restrict__ rel,
                               const int* __restrict__ offs, int* __restrict__ cursor,
                               const int* __restrict__ cnt_rd,
                               uint2* __restrict__ meta)
{
  int e = blockIdx.x * 256 + threadIdx.x;
  int s = ec[e];
  int d = ec[NEDGE + e];
  int r = rel[e];
  int p = offs[d] + atomicAdd(&cursor[d], 1);
  float inv = 1.0f / (float)cnt_rd[(r << 15) + d];
  uint2 m; m.x = ((unsigned int)s << 4) | (unsigned int)r;
  m.y = __float_as_uint(inv);
  meta[p] = m;
}

// -------- Wt[n][k] = stacked [basis;root]^T via LDS transpose, fp32 -> bf16
__global__ __launch_bounds__(256) void build_wt3(
    const float* __restrict__ basis,   // [1024,256] fp32 (= [4,256,256])
    const float* __restrict__ root,    // [256,256] fp32
    unsigned short* __restrict__ Wt)   // [256, KW] bf16
{
  __shared__ float tile[64][65];
  int t = threadIdx.x;
  int k0 = blockIdx.x * 64;            // 20 blocks
  int n0 = blockIdx.y * 64;            // 4 blocks
  int tn = t & 63, tk = t >> 6;
#pragma unroll
  for (int i = 0; i < 64; i += 4){
    int k = k0 + tk + i;
    float v = (k < KBASE) ? basis[(size_t)k * 256 + n0 + tn]
                          : root[(size_t)(k - KBASE) * 256 + n0 + tn];
    tile[tk + i][tn] = v;
  }
  __syncthreads();
#pragma unroll
  for (int i = 0; i < 64; i += 4){
    int n = n0 + tk + i;
    Wt[(size_t)n * KW + k0 + tn] = f2bf(tile[tn][tk + i]);
  }
}

// --------- fused comp-weighted segment sums: z[d,b,:] one wave per dst node
__global__ __launch_bounds__(256) void agg3(
    const unsigned short* __restrict__ Xin,   // [N,256] bf16
    const int* __restrict__ offs,             // [N+1]
    const uint2* __restrict__ meta,           // packed (src<<4|r, inv)
    const float* __restrict__ comp,           // [NREL*NBASES] fp32
    unsigned short* __restrict__ z)           // [N, KBASE] bf16
{
  __shared__ float scomp[NREL * NBASES];
  int t = threadIdx.x;
  if (t < NREL * NBASES) scomp[t] = comp[t];
  __syncthreads();
  int d = blockIdx.x * 4 + (t >> 6);
  int col = (t & 63) * 4;

  float acc[NBASES][4] = {};
  int e0 = offs[d], e1 = offs[d + 1];
  for (int e = e0; e < e1; ++e){
    uint2 md = meta[e];
    int s = (int)(md.x >> 4);
    int r = (int)(md.x & 15u);
    float inv = __uint_as_float(md.y);
    ushort4 v = *(const ushort4*)(Xin + (size_t)s * 256 + col);
    float x0 = bf2f(v.x), x1 = bf2f(v.y), x2 = bf2f(v.z), x3 = bf2f(v.w);
    const float* c = scomp + r * NBASES;
#pragma unroll
    for (int b = 0; b < NBASES; b++){
      float w = inv * c[b];
      acc[b][0] += w * x0; acc[b][1] += w * x1;
      acc[b][2] += w * x2; acc[b][3] += w * x3;
    }
  }
#pragma unroll
  for (int b = 0; b < NBASES; b++){
    ushort4 o;
    o.x = f2bf(acc[b][0]); o.y = f2bf(acc[b][1]);
    o.z = f2bf(acc[b][2]); o.w = f2bf(acc[b][3]);
    *(ushort4*)(z + (size_t)d * KBASE + b * 256 + col) = o;
  }
}

// --------------- MFMA GEMM: Y[M,256] = [z | ext] @ Wt^T + bias  (K = 1280)
// mode 1: outh = relu(v) bf16 ; mode 2: outf = v fp32
// LDS k-slot XOR swizzle: granule (row, kc) lives at slot (kc + (row>>1))&3
__global__ __launch_bounds__(256) void gemm3(
    const unsigned short* __restrict__ A0,   // z [M,KBASE]
    const unsigned short* __restrict__ A1,   // ext [M,256]
    const unsigned short* __restrict__ Wt,   // [256,KW]
    const float* __restrict__ bias,
    unsigned short* __restrict__ outh,
    float* __restrict__ outf,
    int mode)
{
  __shared__ __attribute__((aligned(16))) short As[128 * 32];
  __shared__ __attribute__((aligned(16))) short Bs[128 * 32];
  int tid  = threadIdx.x;
  int m0   = blockIdx.x * 128;
  int n0   = blockIdx.y * 128;
  int lane = tid & 63;
  int wave = tid >> 6;
  int wm = wave & 1, wn = wave >> 1;
  int lq = lane >> 4, lr = lane & 15;

  f32x4 zero = {0.f, 0.f, 0.f, 0.f};
  f32x4 acc[4][4];
#pragma unroll
  for (int i = 0; i < 4; i++)
#pragma unroll
    for (int j = 0; j < 4; j++) acc[i][j] = zero;

  for (int k0 = 0; k0 < KW; k0 += 32){
    __syncthreads();
#pragma unroll
    for (int i = 0; i < 2; i++){
      int g = tid + i * 256;                 // LDS granule id 0..511 (lane-linear)
      int row = g >> 2;
      int kc = ((g & 3) - (g >> 3)) & 3;     // inverse of slot swizzle
      const unsigned short* ga;
      if (k0 < KBASE)
        ga = A0 + (size_t)(m0 + row) * KBASE + k0 + kc * 8;
      else
        ga = A1 + (size_t)(m0 + row) * 256 + (k0 - KBASE) + kc * 8;
      gll16(ga, As + g * 8);
      const unsigned short* gb = Wt + (size_t)(n0 + row) * KW + k0 + kc * 8;
      gll16(gb, Bs + g * 8);
    }
    __syncthreads();

    bf16x8 af[4], bfr[4];
#pragma unroll
    for (int i = 0; i < 4; i++){
      int row = wm * 64 + i * 16 + lr;
      af[i] = *(const bf16x8*)(As + row * 32 + (((lq + (row >> 1)) & 3) * 8));
    }
#pragma unroll
    for (int j = 0; j < 4; j++){
      int row = wn * 64 + j * 16 + lr;
      bfr[j] = *(const bf16x8*)(Bs + row * 32 + (((lq + (row >> 1)) & 3) * 8));
    }
#pragma unroll
    for (int i = 0; i < 4; i++)
#pragma unroll
      for (int j = 0; j < 4; j++)
        acc[i][j] = __builtin_amdgcn_mfma_f32_16x16x32_bf16(af[i], bfr[j], acc[i][j], 0, 0, 0);
  }

  // C/D mapping: col=lane&15, row=(lane>>4)*4+reg  [m89/m91]
#pragma unroll
  for (int i = 0; i < 4; i++)
#pragma unroll
    for (int j = 0; j < 4; j++)
#pragma unroll
      for (int r = 0; r < 4; r++){
        int gm = m0 + wm * 64 + i * 16 + lq * 4 + r;
        int gn = n0 + wn * 64 + j * 16 + lr;
        float v = acc[i][j][r] + bias[gn];
        size_t idx = (size_t)gm * 256 + gn;
        if (mode == 1) outh[idx] = f2bf(fmaxf(v, 0.f));
        else           outf[idx] = v;
      }
}

// ---------------------------------------------------------------------------
extern "C" void kernel_launch(void* const* d_in, const int* in_sizes, int n_in,
                              void* d_out, int out_size, void* d_ws, size_t ws_size,
                              hipStream_t stream)
{
  const float* x      = (const float*)d_in[0];
  const int*   ec     = (const int*)d_in[3];
  const int*   rel    = (const int*)d_in[4];
  const float* basis0 = (const float*)d_in[5];
  const float* comp0  = (const float*)d_in[6];
  const float* root0  = (const float*)d_in[7];
  const float* bias0  = (const float*)d_in[8];
  const float* basis1 = (const float*)d_in[9];
  const float* comp1  = (const float*)d_in[10];
  const float* root1  = (const float*)d_in[11];
  const float* bias1  = (const float*)d_in[12];

  char* p = (char*)d_ws;
  unsigned short* z  = (unsigned short*)p; p += (size_t)NNODES * KBASE * 2;   // 67.1 MB
  unsigned short* Xh = (unsigned short*)p; p += (size_t)NNODES * DIM * 2;     // 16.8
  unsigned short* h  = (unsigned short*)p; p += (size_t)NNODES * DIM * 2;     // 16.8
  unsigned short* Wt = (unsigned short*)p; p += (size_t)256 * KW * 2;         // 0.66
  uint2* meta  = (uint2*)p; p += (size_t)NEDGE * 8;                           // 4.2
  int* cnt_rd  = (int*)p;   p += (size_t)NREL * NNODES * 4;                   // 1.3
  int* deg     = (int*)p;   p += (size_t)NNODES * 4;
  int* cursor  = (int*)p;   p += (size_t)NNODES * 4;
  int* offs    = (int*)p;   p += (size_t)(NNODES + 1) * 4;

  // zero cnt_rd + deg + cursor (contiguous)
  hipMemsetAsync(cnt_rd, 0, ((size_t)NREL * NNODES + 2 * (size_t)NNODES) * 4, stream);

  // ---- graph preprocessing (shared by both layers) ----
  hist_kernel   <<<NEDGE / 256, 256, 0, stream>>>(ec, rel, cnt_rd, deg);
  scan_kernel   <<<1, 1024, 0, stream>>>(deg, offs);
  scatter_kernel<<<NEDGE / 256, 256, 0, stream>>>(ec, rel, offs, cursor, cnt_rd, meta);

  conv_kernel<<<(NNODES * DIM / 4) / 256, 256, 0, stream>>>(x, Xh);

  dim3 wgrid(KW / 64, 256 / 64);
  dim3 ggrid(NNODES / 128, 2);

  // ---- layer 0 ----
  build_wt3<<<wgrid, 256, 0, stream>>>(basis0, root0, Wt);
  agg3<<<NNODES / 4, 256, 0, stream>>>(Xh, offs, meta, comp0, z);
  gemm3<<<ggrid, 256, 0, stream>>>(z, Xh, Wt, bias0, h, nullptr, 1);

  // ---- layer 1 ----
  build_wt3<<<wgrid, 256, 0, stream>>>(basis1, root1, Wt);
  agg3<<<NNODES / 4, 256, 0, stream>>>(h, offs, meta, comp1, z);
  gemm3<<<ggrid, 256, 0, stream>>>(z, h, Wt, bias1, nullptr, (float*)d_out, 2);
}

// Round 5
// 332.981 us; speedup vs baseline: 1.8766x; 1.3089x over previous
//
#include <hip/hip_runtime.h>
#include <stdint.h>

#define NNODES 32768
#define NREL 10
#define NBASES 4
#define DIM 256
#define NEDGE 524288
#define KW 1280                 /* 4*256 basis + 256 root */
#define KBASE 1024              /* z width */

typedef __attribute__((ext_vector_type(8))) short bf16x8;
typedef __attribute__((ext_vector_type(4))) float f32x4;

__device__ __forceinline__ float bf2f(unsigned short u){
  union { unsigned int i; float f; } v; v.i = ((unsigned int)u) << 16; return v.f;
}
__device__ __forceinline__ unsigned short f2bf(float f){
  union { float f; unsigned int i; } v; v.f = f;
  unsigned int x = v.i;
  unsigned int r = (x + 0x7FFFu + ((x >> 16) & 1u)) >> 16;
  return (unsigned short)r;
}
__device__ __forceinline__ void gll16(const void* g, void* l){
  __builtin_amdgcn_global_load_lds((const __attribute__((address_space(1))) void*)g,
                                   (__attribute__((address_space(3))) void*)l, 16, 0, 0);
}

// ----------------------------------------------------- fp32 -> bf16 convert
__global__ __launch_bounds__(256) void conv_kernel(const float* __restrict__ in,
                                                   unsigned short* __restrict__ out)
{
  int i = blockIdx.x * 256 + threadIdx.x;
  float4 v = ((const float4*)in)[i];
  ushort4 o; o.x = f2bf(v.x); o.y = f2bf(v.y); o.z = f2bf(v.z); o.w = f2bf(v.w);
  ((ushort4*)out)[i] = o;
}

// ------------------------------------------------ histogram: per-(r,d) only
__global__ void hist_kernel(const int* __restrict__ ec, const int* __restrict__ rel,
                            int* __restrict__ cnt_rd)
{
  int e = blockIdx.x * 256 + threadIdx.x;
  int d = ec[NEDGE + e];
  int r = rel[e];
  atomicAdd(&cnt_rd[(r << 15) + d], 1);
}

// ---------------- 3-phase exclusive scan over deg (deg = sum_r cnt_rd[r,d])
__global__ __launch_bounds__(1024) void scan1(const int* __restrict__ cnt_rd,
                                              int* __restrict__ offs, int* __restrict__ blksum)
{
  __shared__ int sh[1024];
  int tid = threadIdx.x; int gid = blockIdx.x * 1024 + tid;
  int v = 0;
#pragma unroll
  for (int r = 0; r < NREL; r++) v += cnt_rd[(r << 15) + gid];
  sh[tid] = v; __syncthreads();
  for (int off = 1; off < 1024; off <<= 1){
    int t = (tid >= off) ? sh[tid - off] : 0;
    __syncthreads(); sh[tid] += t; __syncthreads();
  }
  offs[gid] = sh[tid] - v;
  if (tid == 1023) blksum[blockIdx.x] = sh[1023];
}
__global__ __launch_bounds__(64) void scan2(int* __restrict__ blksum)
{
  __shared__ int sh[64];
  int tid = threadIdx.x;
  int v = (tid < NNODES / 1024) ? blksum[tid] : 0;
  sh[tid] = v; __syncthreads();
  for (int off = 1; off < 64; off <<= 1){
    int t = (tid >= off) ? sh[tid - off] : 0;
    __syncthreads(); sh[tid] += t; __syncthreads();
  }
  if (tid < NNODES / 1024) blksum[tid] = sh[tid] - v;
}
__global__ __launch_bounds__(1024) void scan3(int* __restrict__ offs, const int* __restrict__ blksum)
{
  int gid = blockIdx.x * 1024 + threadIdx.x;
  offs[gid] += blksum[blockIdx.x];
  if (gid == 0) offs[NNODES] = NEDGE;
}

// --------------------------- bucket scatter: sort by dst, pack (src,rel,inv)
__global__ void scatter_kernel(const int* __restrict__ ec, const int* __restrict__ rel,
                               const int* __restrict__ offs, int* __restrict__ cursor,
                               const int* __restrict__ cnt_rd,
                               uint2* __restrict__ meta)
{
  int e = blockIdx.x * 256 + threadIdx.x;
  int s = ec[e];
  int d = ec[NEDGE + e];
  int r = rel[e];
  int p = offs[d] + atomicAdd(&cursor[d], 1);
  float inv = 1.0f / (float)cnt_rd[(r << 15) + d];
  uint2 m; m.x = ((unsigned int)s << 4) | (unsigned int)r;
  m.y = __float_as_uint(inv);
  meta[p] = m;
}

// -------- Wt[n][k] = stacked [basis;root]^T via LDS transpose, fp32 -> bf16
__global__ __launch_bounds__(256) void build_wt3(
    const float* __restrict__ basis,   // [1024,256] fp32 (= [4,256,256])
    const float* __restrict__ root,    // [256,256] fp32
    unsigned short* __restrict__ Wt)   // [256, KW] bf16
{
  __shared__ float tile[64][65];
  int t = threadIdx.x;
  int k0 = blockIdx.x * 64;            // 20 blocks
  int n0 = blockIdx.y * 64;            // 4 blocks
  int tn = t & 63, tk = t >> 6;
#pragma unroll
  for (int i = 0; i < 64; i += 4){
    int k = k0 + tk + i;
    float v = (k < KBASE) ? basis[(size_t)k * 256 + n0 + tn]
                          : root[(size_t)(k - KBASE) * 256 + n0 + tn];
    tile[tk + i][tn] = v;
  }
  __syncthreads();
#pragma unroll
  for (int i = 0; i < 64; i += 4){
    int n = n0 + tk + i;
    Wt[(size_t)n * KW + k0 + tn] = f2bf(tile[tn][tk + i]);
  }
}

// --------- fused comp-weighted segment sums, 4-deep pipelined gather
__global__ __launch_bounds__(256) void agg4(
    const unsigned short* __restrict__ Xin,   // [N,256] bf16
    const int* __restrict__ offs,             // [N+1]
    const uint2* __restrict__ meta,           // packed (src<<4|r, inv)
    const float* __restrict__ comp,           // [NREL*NBASES] fp32
    unsigned short* __restrict__ z)           // [N, KBASE] bf16
{
  __shared__ float scomp[NREL * NBASES];
  int t = threadIdx.x;
  if (t < NREL * NBASES) scomp[t] = comp[t];
  __syncthreads();
  int d = blockIdx.x * 4 + (t >> 6);
  int col = (t & 63) * 4;

  float acc[NBASES][4] = {};
  int e0 = offs[d], e1 = offs[d + 1];
  int e = e0;
  for (; e + 3 < e1; e += 4){
    uint2 m0 = meta[e], m1 = meta[e + 1], m2 = meta[e + 2], m3 = meta[e + 3];
    ushort4 v0 = *(const ushort4*)(Xin + ((size_t)(m0.x >> 4)) * 256 + col);
    ushort4 v1 = *(const ushort4*)(Xin + ((size_t)(m1.x >> 4)) * 256 + col);
    ushort4 v2 = *(const ushort4*)(Xin + ((size_t)(m2.x >> 4)) * 256 + col);
    ushort4 v3 = *(const ushort4*)(Xin + ((size_t)(m3.x >> 4)) * 256 + col);
#pragma unroll
    for (int b = 0; b < NBASES; b++){
      float w0 = __uint_as_float(m0.y) * scomp[(m0.x & 15u) * NBASES + b];
      float w1 = __uint_as_float(m1.y) * scomp[(m1.x & 15u) * NBASES + b];
      float w2 = __uint_as_float(m2.y) * scomp[(m2.x & 15u) * NBASES + b];
      float w3 = __uint_as_float(m3.y) * scomp[(m3.x & 15u) * NBASES + b];
      acc[b][0] += w0 * bf2f(v0.x) + w1 * bf2f(v1.x) + w2 * bf2f(v2.x) + w3 * bf2f(v3.x);
      acc[b][1] += w0 * bf2f(v0.y) + w1 * bf2f(v1.y) + w2 * bf2f(v2.y) + w3 * bf2f(v3.y);
      acc[b][2] += w0 * bf2f(v0.z) + w1 * bf2f(v1.z) + w2 * bf2f(v2.z) + w3 * bf2f(v3.z);
      acc[b][3] += w0 * bf2f(v0.w) + w1 * bf2f(v1.w) + w2 * bf2f(v2.w) + w3 * bf2f(v3.w);
    }
  }
  for (; e < e1; ++e){
    uint2 md = meta[e];
    int s = (int)(md.x >> 4);
    float inv = __uint_as_float(md.y);
    ushort4 v = *(const ushort4*)(Xin + (size_t)s * 256 + col);
    const float* c = scomp + (md.x & 15u) * NBASES;
#pragma unroll
    for (int b = 0; b < NBASES; b++){
      float w = inv * c[b];
      acc[b][0] += w * bf2f(v.x); acc[b][1] += w * bf2f(v.y);
      acc[b][2] += w * bf2f(v.z); acc[b][3] += w * bf2f(v.w);
    }
  }
#pragma unroll
  for (int b = 0; b < NBASES; b++){
    ushort4 o;
    o.x = f2bf(acc[b][0]); o.y = f2bf(acc[b][1]);
    o.z = f2bf(acc[b][2]); o.w = f2bf(acc[b][3]);
    *(ushort4*)(z + (size_t)d * KBASE + b * 256 + col) = o;
  }
}

// ---- MFMA GEMM: Y[M,256] = [z | ext] @ Wt^T + bias  (tile 64m x 256n, K=1280)
// mode 1: outh = relu(v) bf16 ; mode 2: outf = v fp32
// LDS k-slot XOR swizzle: granule (row, kc) lives at slot (kc + (row>>1))&3
__global__ __launch_bounds__(256) void gemm4(
    const unsigned short* __restrict__ A0,   // z [M,KBASE]
    const unsigned short* __restrict__ A1,   // ext [M,256]
    const unsigned short* __restrict__ Wt,   // [256,KW]
    const float* __restrict__ bias,
    unsigned short* __restrict__ outh,
    float* __restrict__ outf,
    int mode)
{
  __shared__ __attribute__((aligned(16))) short As[64 * 32];    // 4 KB
  __shared__ __attribute__((aligned(16))) short Bs[256 * 32];   // 16 KB
  int tid  = threadIdx.x;
  int m0   = blockIdx.x * 64;
  int lane = tid & 63;
  int wn   = tid >> 6;               // wave = n-slice 0..3
  int lq = lane >> 4, lr = lane & 15;

  f32x4 zero = {0.f, 0.f, 0.f, 0.f};
  f32x4 acc[4][4];
#pragma unroll
  for (int i = 0; i < 4; i++)
#pragma unroll
    for (int j = 0; j < 4; j++) acc[i][j] = zero;

  // A staging source params (row = tid>>2, kc = inverse swizzle)
  int arow = tid >> 2;
  int akc  = ((tid & 3) - (tid >> 3)) & 3;

  for (int k0 = 0; k0 < KW; k0 += 32){
    __syncthreads();
    {
      const unsigned short* ga;
      if (k0 < KBASE) ga = A0 + (size_t)(m0 + arow) * KBASE + k0 + akc * 8;
      else            ga = A1 + (size_t)(m0 + arow) * 256 + (k0 - KBASE) + akc * 8;
      gll16(ga, As + tid * 8);
    }
#pragma unroll
    for (int i = 0; i < 4; i++){
      int gb  = tid + i * 256;             // 0..1023 B granules
      int row = gb >> 2;
      int kc  = ((gb & 3) - (gb >> 3)) & 3;
      gll16(Wt + (size_t)row * KW + k0 + kc * 8, Bs + gb * 8);
    }
    __syncthreads();

    bf16x8 af[4], bfr[4];
#pragma unroll
    for (int i = 0; i < 4; i++){
      int row = i * 16 + lr;
      af[i] = *(const bf16x8*)(As + row * 32 + (((lq + (row >> 1)) & 3) * 8));
    }
#pragma unroll
    for (int j = 0; j < 4; j++){
      int row = wn * 64 + j * 16 + lr;
      bfr[j] = *(const bf16x8*)(Bs + row * 32 + (((lq + (row >> 1)) & 3) * 8));
    }
#pragma unroll
    for (int i = 0; i < 4; i++)
#pragma unroll
      for (int j = 0; j < 4; j++)
        acc[i][j] = __builtin_amdgcn_mfma_f32_16x16x32_bf16(af[i], bfr[j], acc[i][j], 0, 0, 0);
  }

  // C/D mapping: col=lane&15, row=(lane>>4)*4+reg  [m89/m91]
#pragma unroll
  for (int i = 0; i < 4; i++)
#pragma unroll
    for (int j = 0; j < 4; j++)
#pragma unroll
      for (int r = 0; r < 4; r++){
        int gm = m0 + i * 16 + lq * 4 + r;
        int gn = wn * 64 + j * 16 + lr;
        float v = acc[i][j][r] + bias[gn];
        size_t idx = (size_t)gm * 256 + gn;
        if (mode == 1) outh[idx] = f2bf(fmaxf(v, 0.f));
        else           outf[idx] = v;
      }
}

// ---------------------------------------------------------------------------
extern "C" void kernel_launch(void* const* d_in, const int* in_sizes, int n_in,
                              void* d_out, int out_size, void* d_ws, size_t ws_size,
                              hipStream_t stream)
{
  const float* x      = (const float*)d_in[0];
  const int*   ec     = (const int*)d_in[3];
  const int*   rel    = (const int*)d_in[4];
  const float* basis0 = (const float*)d_in[5];
  const float* comp0  = (const float*)d_in[6];
  const float* root0  = (const float*)d_in[7];
  const float* bias0  = (const float*)d_in[8];
  const float* basis1 = (const float*)d_in[9];
  const float* comp1  = (const float*)d_in[10];
  const float* root1  = (const float*)d_in[11];
  const float* bias1  = (const float*)d_in[12];

  char* p = (char*)d_ws;
  unsigned short* z  = (unsigned short*)p; p += (size_t)NNODES * KBASE * 2;   // 67.1 MB
  unsigned short* Xh = (unsigned short*)p; p += (size_t)NNODES * DIM * 2;     // 16.8
  unsigned short* h  = (unsigned short*)p; p += (size_t)NNODES * DIM * 2;     // 16.8
  unsigned short* Wt = (unsigned short*)p; p += (size_t)256 * KW * 2;         // 0.66
  uint2* meta  = (uint2*)p; p += (size_t)NEDGE * 8;                           // 4.2
  int* cnt_rd  = (int*)p;   p += (size_t)NREL * NNODES * 4;                   // 1.3
  int* cursor  = (int*)p;   p += (size_t)NNODES * 4;
  int* offs    = (int*)p;   p += (size_t)(NNODES + 1) * 4;
  int* blksum  = (int*)p;   p += 1024;

  // zero cnt_rd + cursor (contiguous)
  hipMemsetAsync(cnt_rd, 0, ((size_t)NREL * NNODES + (size_t)NNODES) * 4, stream);

  // ---- graph preprocessing (shared by both layers) ----
  hist_kernel   <<<NEDGE / 256, 256, 0, stream>>>(ec, rel, cnt_rd);
  scan1         <<<NNODES / 1024, 1024, 0, stream>>>(cnt_rd, offs, blksum);
  scan2         <<<1, 64, 0, stream>>>(blksum);
  scan3         <<<NNODES / 1024, 1024, 0, stream>>>(offs, blksum);
  scatter_kernel<<<NEDGE / 256, 256, 0, stream>>>(ec, rel, offs, cursor, cnt_rd, meta);

  conv_kernel<<<(NNODES * DIM / 4) / 256, 256, 0, stream>>>(x, Xh);

  dim3 wgrid(KW / 64, 256 / 64);

  // ---- layer 0 ----
  build_wt3<<<wgrid, 256, 0, stream>>>(basis0, root0, Wt);
  agg4<<<NNODES / 4, 256, 0, stream>>>(Xh, offs, meta, comp0, z);
  gemm4<<<NNODES / 64, 256, 0, stream>>>(z, Xh, Wt, bias0, h, nullptr, 1);

  // ---- layer 1 ----
  build_wt3<<<wgrid, 256, 0, stream>>>(basis1, root1, Wt);
  agg4<<<NNODES / 4, 256, 0, stream>>>(h, offs, meta, comp1, z);
  gemm4<<<NNODES / 64, 256, 0, stream>>>(z, h, Wt, bias1, nullptr, (float*)d_out, 2);
}